// Round 2
// baseline (821.637 us; speedup 1.0000x reference)
//
#include <hip/hip_runtime.h>
#include <hip/hip_bf16.h>

#define NROWS 50000
#define CDIM 8
#define XDIM 256
#define HDIM 256

typedef __attribute__((ext_vector_type(8))) short bf16x8;  // MFMA bf16 operand (4 VGPRs)
typedef __attribute__((ext_vector_type(4))) float f32x4;   // MFMA accumulator

// fp32 -> bf16 round-to-nearest-even
__device__ __forceinline__ unsigned short f2bf_rne(float f) {
    unsigned int u = __builtin_bit_cast(unsigned int, f);
    u += 0x7fffu + ((u >> 16) & 1u);
    return (unsigned short)(u >> 16);
}

__device__ __forceinline__ bf16x8 pack8(const f32x4 a, const f32x4 b) {
    bf16x8 r;
    r[0] = (short)f2bf_rne(a[0]);
    r[1] = (short)f2bf_rne(a[1]);
    r[2] = (short)f2bf_rne(a[2]);
    r[3] = (short)f2bf_rne(a[3]);
    r[4] = (short)f2bf_rne(b[0]);
    r[5] = (short)f2bf_rne(b[1]);
    r[6] = (short)f2bf_rne(b[2]);
    r[7] = (short)f2bf_rne(b[3]);
    return r;
}

// Pack W_left / W_right / W_top (each [256,256] fp32, row-major [x][h]) into
// MFMA A-operand fragment layout in ws:
//   frag index = ((seg*8 + xc)*16 + ht), 64 lanes x 8 bf16 each (16 B/lane).
//   value[lane][j] = W_seg[ xc*32 + (lane>>4)*8 + j ][ ht*16 + (lane&15) ]
// 384 tiles * 1024 B = 384 KiB total.
__global__ __launch_bounds__(256) void pack_weights(
        const float* __restrict__ Wl, const float* __restrict__ Wr,
        const float* __restrict__ Wt, bf16x8* __restrict__ wp) {
    int t = blockIdx.x * 256 + threadIdx.x;   // 24576 threads total
    int lane = t & 63;
    int tile = t >> 6;          // 0..383
    int ht  = tile & 15;
    int sx  = tile >> 4;        // seg*8 + xc
    int xc  = sx & 7;
    int seg = sx >> 3;
    const float* __restrict__ W = (seg == 0) ? Wl : (seg == 1) ? Wr : Wt;
    int x0 = xc * 32 + (lane >> 4) * 8;
    int h  = ht * 16 + (lane & 15);
    bf16x8 frag;
#pragma unroll
    for (int j = 0; j < 8; ++j)
        frag[j] = (short)f2bf_rne(W[(size_t)(x0 + j) * HDIM + h]);
    wp[t] = frag;
}

// MEASUREMENT ROUND: exact round-0 main kernel, but the whole body executes
// TWICE (idempotent: pass 2 recomputes and overwrites identical values).
// The doubled dispatch (~2x K0) should cross the ~247 us top-5 cutoff and
// expose the kernel's own rocprof counters. The memory clobber between reps
// prevents DSE/CSE of pass 0 (rule #17).
__global__ __launch_bounds__(256) void tbcnn_main(
        const float* __restrict__ child, const float* __restrict__ parent,
        const bf16x8* __restrict__ wp, const float* __restrict__ bias,
        float* __restrict__ out) {
    const int wave = threadIdx.x >> 6;
    const int lane = threadIdx.x & 63;
    const int wtask = blockIdx.x * 4 + wave;
    const int row0 = wtask * 16;
    if (row0 >= NROWS) return;            // 50000 % 16 == 0: full tiles only

    const int rmod = lane & 15;           // row_local (B-operand n / D col)
    const int quad = lane >> 4;           // k-octet selector
    const int row  = row0 + rmod;

    const float* __restrict__ chrow = child  + (size_t)row * (CDIM * XDIM);
    const float* __restrict__ prow  = parent + (size_t)row * XDIM;

    // positional tree weights, fp32 exact same constants as reference
    const float lwt[8] = {7.f/7.f, 6.f/7.f, 5.f/7.f, 4.f/7.f, 3.f/7.f, 2.f/7.f, 1.f/7.f, 0.f/7.f};
    const float rwt[8] = {0.f/7.f, 1.f/7.f, 2.f/7.f, 3.f/7.f, 4.f/7.f, 5.f/7.f, 6.f/7.f, 7.f/7.f};

#pragma unroll 1
    for (int rep = 0; rep < 2; ++rep) {
        asm volatile("" ::: "memory");   // forbid merging/eliding the passes

        f32x4 acc[16];
#pragma unroll
        for (int t = 0; t < 16; ++t) acc[t] = (f32x4){0.f, 0.f, 0.f, 0.f};

#pragma unroll 1
        for (int xc = 0; xc < 8; ++xc) {
            const int x0 = xc * 32 + quad * 8;   // this lane's 8 x's

            // ---- compute s_left / s_right for lane's (row, 8 x's) in fp32 ----
            f32x4 sl0 = (f32x4){0.f,0.f,0.f,0.f}, sl1 = (f32x4){0.f,0.f,0.f,0.f};
            f32x4 sr0 = (f32x4){0.f,0.f,0.f,0.f}, sr1 = (f32x4){0.f,0.f,0.f,0.f};
#pragma unroll
            for (int c = 0; c < CDIM; ++c) {
                const f32x4* p = (const f32x4*)(chrow + (size_t)c * XDIM + x0);
                f32x4 a = p[0];
                f32x4 b = p[1];
                sl0 += a * lwt[c];  sl1 += b * lwt[c];
                sr0 += a * rwt[c];  sr1 += b * rwt[c];
            }
            const f32x4* pp = (const f32x4*)(prow + x0);
            f32x4 p0 = pp[0];
            f32x4 p1 = pp[1];

            // B-operand fragments: n = lane&15 = row_local, k = quad*8+j = x
            bf16x8 fL = pack8(sl0, sl1);
            bf16x8 fR = pack8(sr0, sr1);
            bf16x8 fP = pack8(p0, p1);

            // ---- 3 k-steps (left / right / top), 16 h-tiles each ----
            const bf16x8* wL = wp + ((size_t)((0 * 8 + xc) * 16)) * 64 + lane;
            const bf16x8* wR = wp + ((size_t)((1 * 8 + xc) * 16)) * 64 + lane;
            const bf16x8* wT = wp + ((size_t)((2 * 8 + xc) * 16)) * 64 + lane;
#pragma unroll
            for (int ht = 0; ht < 16; ++ht)
                acc[ht] = __builtin_amdgcn_mfma_f32_16x16x32_bf16(wL[ht * 64], fL, acc[ht], 0, 0, 0);
#pragma unroll
            for (int ht = 0; ht < 16; ++ht)
                acc[ht] = __builtin_amdgcn_mfma_f32_16x16x32_bf16(wR[ht * 64], fR, acc[ht], 0, 0, 0);
#pragma unroll
            for (int ht = 0; ht < 16; ++ht)
                acc[ht] = __builtin_amdgcn_mfma_f32_16x16x32_bf16(wT[ht * 64], fP, acc[ht], 0, 0, 0);
        }

        // ---- epilogue: bias + relu, float4 stores (4 consecutive h per tile) ----
        float* __restrict__ orow = out + (size_t)row * HDIM;   // D col = lane&15
#pragma unroll
        for (int ht = 0; ht < 16; ++ht) {
            const int h = ht * 16 + quad * 4;
            f32x4 b4 = *(const f32x4*)(bias + h);
            f32x4 v = acc[ht];
            v[0] = fmaxf(v[0] + b4[0], 0.f);
            v[1] = fmaxf(v[1] + b4[1], 0.f);
            v[2] = fmaxf(v[2] + b4[2], 0.f);
            v[3] = fmaxf(v[3] + b4[3], 0.f);
            *(f32x4*)(orow + h) = v;
        }
    }
}

// Correct-but-slow fallback if ws is too small for the packed weights.
__global__ __launch_bounds__(256) void tbcnn_fallback(
        const float* __restrict__ child, const float* __restrict__ parent,
        const float* __restrict__ Wl, const float* __restrict__ Wr,
        const float* __restrict__ Wt, const float* __restrict__ bias,
        float* __restrict__ out) {
    __shared__ float sl[XDIM], sr[XDIM], sp[XDIM];
    const int n = blockIdx.x;
    const int h = threadIdx.x;
    const float lwt[8] = {7.f/7.f, 6.f/7.f, 5.f/7.f, 4.f/7.f, 3.f/7.f, 2.f/7.f, 1.f/7.f, 0.f/7.f};
    const float* ch = child + (size_t)n * (CDIM * XDIM);
    float al = 0.f;
#pragma unroll
    for (int c = 0; c < CDIM; ++c) {
        float v = ch[c * XDIM + h];
        al += lwt[c] * v;
    }
    float ar = 0.f;
    const float rwt[8] = {0.f/7.f, 1.f/7.f, 2.f/7.f, 3.f/7.f, 4.f/7.f, 5.f/7.f, 6.f/7.f, 7.f/7.f};
#pragma unroll
    for (int c = 0; c < CDIM; ++c) ar += rwt[c] * ch[c * XDIM + h];
    sl[h] = al; sr[h] = ar; sp[h] = parent[(size_t)n * XDIM + h];
    __syncthreads();
    float a = bias[h];
    for (int x = 0; x < XDIM; ++x)
        a += sl[x] * Wl[(size_t)x * HDIM + h] + sr[x] * Wr[(size_t)x * HDIM + h]
           + sp[x] * Wt[(size_t)x * HDIM + h];
    out[(size_t)n * HDIM + h] = fmaxf(a, 0.f);
}

extern "C" void kernel_launch(void* const* d_in, const int* in_sizes, int n_in,
                              void* d_out, int out_size, void* d_ws, size_t ws_size,
                              hipStream_t stream) {
    const float* child  = (const float*)d_in[0];
    const float* parent = (const float*)d_in[1];
    const float* Wl     = (const float*)d_in[2];
    const float* Wr     = (const float*)d_in[3];
    const float* Wt     = (const float*)d_in[4];
    const float* bias   = (const float*)d_in[5];
    float* out = (float*)d_out;

    const size_t wp_bytes = (size_t)3 * XDIM * HDIM * sizeof(unsigned short); // 384 KiB
    if (ws_size >= wp_bytes) {
        bf16x8* wp = (bf16x8*)d_ws;
        pack_weights<<<96, 256, 0, stream>>>(Wl, Wr, Wt, wp);
        const int n_wtasks = NROWS / 16;                 // 3125
        const int n_blocks = (n_wtasks + 3) / 4;         // 782
        tbcnn_main<<<n_blocks, 256, 0, stream>>>(child, parent, wp, bias, out);
    } else {
        tbcnn_fallback<<<NROWS, 256, 0, stream>>>(child, parent, Wl, Wr, Wt, bias, out);
    }
}

// Round 3
// 612.449 us; speedup vs baseline: 1.3416x; 1.3416x over previous
//
#include <hip/hip_runtime.h>
#include <hip/hip_bf16.h>

#define NROWS 50000
#define CDIM 8
#define XDIM 256
#define HDIM 256

typedef __attribute__((ext_vector_type(8))) short bf16x8;  // MFMA bf16 operand (4 VGPRs)
typedef __attribute__((ext_vector_type(4))) float f32x4;   // MFMA accumulator

// fp32 -> bf16 round-to-nearest-even
__device__ __forceinline__ unsigned short f2bf_rne(float f) {
    unsigned int u = __builtin_bit_cast(unsigned int, f);
    u += 0x7fffu + ((u >> 16) & 1u);
    return (unsigned short)(u >> 16);
}

__device__ __forceinline__ bf16x8 pack8(const f32x4 a, const f32x4 b) {
    bf16x8 r;
    r[0] = (short)f2bf_rne(a[0]);
    r[1] = (short)f2bf_rne(a[1]);
    r[2] = (short)f2bf_rne(a[2]);
    r[3] = (short)f2bf_rne(a[3]);
    r[4] = (short)f2bf_rne(b[0]);
    r[5] = (short)f2bf_rne(b[1]);
    r[6] = (short)f2bf_rne(b[2]);
    r[7] = (short)f2bf_rne(b[3]);
    return r;
}

// Pack W_left / W_right / W_top (each [256,256] fp32, row-major [x][h]) into
// MFMA A-operand fragment layout in ws:
//   frag index = ((seg*8 + xc)*16 + ht), 64 lanes x 8 bf16 each (16 B/lane).
//   value[lane][j] = W_seg[ xc*32 + (lane>>4)*8 + j ][ ht*16 + (lane&15) ]
// 384 tiles * 1024 B = 384 KiB total.
__global__ __launch_bounds__(256) void pack_weights(
        const float* __restrict__ Wl, const float* __restrict__ Wr,
        const float* __restrict__ Wt, bf16x8* __restrict__ wp) {
    int t = blockIdx.x * 256 + threadIdx.x;   // 24576 threads total
    int lane = t & 63;
    int tile = t >> 6;          // 0..383
    int ht  = tile & 15;
    int sx  = tile >> 4;        // seg*8 + xc
    int xc  = sx & 7;
    int seg = sx >> 3;
    const float* __restrict__ W = (seg == 0) ? Wl : (seg == 1) ? Wr : Wt;
    int x0 = xc * 32 + (lane >> 4) * 8;
    int h  = ht * 16 + (lane & 15);
    bf16x8 frag;
#pragma unroll
    for (int j = 0; j < 8; ++j)
        frag[j] = (short)f2bf_rne(W[(size_t)(x0 + j) * HDIM + h]);
    wp[t] = frag;
}

// ROUND 3: kill the redundant weight traffic (4.6 GiB/pass from L2 -> 0.3 GiB).
// Block = 64 rows (4 row-tiles). Wave w = ALL 4 row-tiles x h-quadrant w
// (h-tiles 4w..4w+3): weight frags loaded once per wave, reused 4x.
// Each wave computes B-fragments for ITS row-tile (compulsory HBM loads only)
// and shares them via a 24 KiB double-buffered LDS buffer; one barrier per xc
// (double buffer makes the pre-overwrite barrier unnecessary: xc+2's write of
// buf p is ordered after xc+1's barrier, which is after every wave's xc reads).
// Accumulation order per output (xc-major, L/R/T inner) identical to round-0.
__global__ __launch_bounds__(256) void tbcnn_main(
        const float* __restrict__ child, const float* __restrict__ parent,
        const bf16x8* __restrict__ wp, const float* __restrict__ bias,
        float* __restrict__ out) {
    __shared__ bf16x8 flds[2][4][3][64];   // [buf][row-tile][seg][lane], 24 KiB

    const int wave = threadIdx.x >> 6;
    const int lane = threadIdx.x & 63;
    const int rmod = lane & 15;           // row_local (B-operand n / D col)
    const int quad = lane >> 4;           // k-octet selector

    const int blk0   = blockIdx.x * 64;
    const int rb_own = blk0 + wave * 16;                 // row-tile this wave stages
    const int row_own = ((rb_own + 16 <= NROWS) ? rb_own : (NROWS - 16)) + rmod;

    const float* __restrict__ chrow = child  + (size_t)row_own * (CDIM * XDIM);
    const float* __restrict__ prow  = parent + (size_t)row_own * XDIM;

    // positional tree weights, fp32 exact same constants as reference
    const float lwt[8] = {7.f/7.f, 6.f/7.f, 5.f/7.f, 4.f/7.f, 3.f/7.f, 2.f/7.f, 1.f/7.f, 0.f/7.f};
    const float rwt[8] = {0.f/7.f, 1.f/7.f, 2.f/7.f, 3.f/7.f, 4.f/7.f, 5.f/7.f, 6.f/7.f, 7.f/7.f};

    f32x4 acc[4][4];   // [row-tile][h-tile within quadrant]
#pragma unroll
    for (int rt = 0; rt < 4; ++rt)
#pragma unroll
        for (int t = 0; t < 4; ++t) acc[rt][t] = (f32x4){0.f, 0.f, 0.f, 0.f};

    // weight tile index: ((seg*8 + xc)*16 + wave*4 + t)*64 + lane
    // per-xc base advances by 16*64 = 1024; seg stride = 8*16*64 = 8192.
    // prefetch xc=0 / seg=0:
    bf16x8 wn[4];
    {
        const bf16x8* wb0 = wp + (size_t)((0 * 16 + wave * 4) * 64 + lane);
#pragma unroll
        for (int t = 0; t < 4; ++t) wn[t] = wb0[t * 64];
    }

#pragma unroll 1
    for (int xc = 0; xc < 8; ++xc) {
        const int p  = xc & 1;
        const int x0 = xc * 32 + quad * 8;   // this lane's 8 x's (staging role)
        const bf16x8* wb = wp + (size_t)((xc * 16 + wave * 4) * 64 + lane);

        // ---- compute own row-tile's B fragments (compulsory HBM traffic) ----
        f32x4 sl0 = (f32x4){0.f,0.f,0.f,0.f}, sl1 = (f32x4){0.f,0.f,0.f,0.f};
        f32x4 sr0 = (f32x4){0.f,0.f,0.f,0.f}, sr1 = (f32x4){0.f,0.f,0.f,0.f};
#pragma unroll
        for (int c = 0; c < CDIM; ++c) {
            const f32x4* cp = (const f32x4*)(chrow + (size_t)c * XDIM + x0);
            f32x4 a = cp[0];
            f32x4 b = cp[1];
            sl0 += a * lwt[c];  sl1 += b * lwt[c];
            sr0 += a * rwt[c];  sr1 += b * rwt[c];
        }
        const f32x4* pp = (const f32x4*)(prow + x0);
        f32x4 p0 = pp[0];
        f32x4 p1 = pp[1];

        flds[p][wave][0][lane] = pack8(sl0, sl1);
        flds[p][wave][1][lane] = pack8(sr0, sr1);
        flds[p][wave][2][lane] = pack8(p0, p1);
        __syncthreads();   // frags[p] for all 4 row-tiles ready

        // ---- MFMA: 3 segs x 4 row-tiles x 4 h-tiles, weights pipelined ----
#pragma unroll
        for (int seg = 0; seg < 3; ++seg) {
            bf16x8 wc[4];
#pragma unroll
            for (int t = 0; t < 4; ++t) wc[t] = wn[t];
            // prefetch next seg (or next xc's seg 0; xc=7 tail reads stay
            // in-bounds inside the 384-tile buffer and are discarded)
            const int noff = (seg < 2) ? (seg + 1) * 8192 : 1024;
#pragma unroll
            for (int t = 0; t < 4; ++t) wn[t] = wb[noff + t * 64];
#pragma unroll
            for (int rt = 0; rt < 4; ++rt) {
                bf16x8 f = flds[p][rt][seg][lane];
#pragma unroll
                for (int t = 0; t < 4; ++t)
                    acc[rt][t] = __builtin_amdgcn_mfma_f32_16x16x32_bf16(wc[t], f, acc[rt][t], 0, 0, 0);
            }
        }
        // no second barrier: next xc writes flds[p^1]
    }

    // ---- epilogue: bias + relu; wave w stores h-quadrant w of all row-tiles ----
#pragma unroll
    for (int rt = 0; rt < 4; ++rt) {
        const int rb = blk0 + rt * 16;
        if (rb + 16 <= NROWS) {
            float* __restrict__ orow = out + (size_t)(rb + rmod) * HDIM;
#pragma unroll
            for (int t = 0; t < 4; ++t) {
                const int h = (wave * 4 + t) * 16 + quad * 4;
                f32x4 b4 = *(const f32x4*)(bias + h);
                f32x4 v = acc[rt][t];
                v[0] = fmaxf(v[0] + b4[0], 0.f);
                v[1] = fmaxf(v[1] + b4[1], 0.f);
                v[2] = fmaxf(v[2] + b4[2], 0.f);
                v[3] = fmaxf(v[3] + b4[3], 0.f);
                *(f32x4*)(orow + h) = v;
            }
        }
    }
}

// Correct-but-slow fallback if ws is too small for the packed weights.
__global__ __launch_bounds__(256) void tbcnn_fallback(
        const float* __restrict__ child, const float* __restrict__ parent,
        const float* __restrict__ Wl, const float* __restrict__ Wr,
        const float* __restrict__ Wt, const float* __restrict__ bias,
        float* __restrict__ out) {
    __shared__ float sl[XDIM], sr[XDIM], sp[XDIM];
    const int n = blockIdx.x;
    const int h = threadIdx.x;
    const float lwt[8] = {7.f/7.f, 6.f/7.f, 5.f/7.f, 4.f/7.f, 3.f/7.f, 2.f/7.f, 1.f/7.f, 0.f/7.f};
    const float rwt[8] = {0.f/7.f, 1.f/7.f, 2.f/7.f, 3.f/7.f, 4.f/7.f, 5.f/7.f, 6.f/7.f, 7.f/7.f};
    const float* ch = child + (size_t)n * (CDIM * XDIM);
    float al = 0.f, ar = 0.f;
#pragma unroll
    for (int c = 0; c < CDIM; ++c) {
        float v = ch[c * XDIM + h];
        al += lwt[c] * v;
        ar += rwt[c] * v;
    }
    sl[h] = al; sr[h] = ar; sp[h] = parent[(size_t)n * XDIM + h];
    __syncthreads();
    float a = bias[h];
    for (int x = 0; x < XDIM; ++x)
        a += sl[x] * Wl[(size_t)x * HDIM + h] + sr[x] * Wr[(size_t)x * HDIM + h]
           + sp[x] * Wt[(size_t)x * HDIM + h];
    out[(size_t)n * HDIM + h] = fmaxf(a, 0.f);
}

extern "C" void kernel_launch(void* const* d_in, const int* in_sizes, int n_in,
                              void* d_out, int out_size, void* d_ws, size_t ws_size,
                              hipStream_t stream) {
    const float* child  = (const float*)d_in[0];
    const float* parent = (const float*)d_in[1];
    const float* Wl     = (const float*)d_in[2];
    const float* Wr     = (const float*)d_in[3];
    const float* Wt     = (const float*)d_in[4];
    const float* bias   = (const float*)d_in[5];
    float* out = (float*)d_out;

    const size_t wp_bytes = (size_t)3 * XDIM * HDIM * sizeof(unsigned short); // 384 KiB
    if (ws_size >= wp_bytes) {
        bf16x8* wp = (bf16x8*)d_ws;
        pack_weights<<<96, 256, 0, stream>>>(Wl, Wr, Wt, wp);
        const int n_blocks = (NROWS + 63) / 64;          // 782 blocks x 64 rows
        tbcnn_main<<<n_blocks, 256, 0, stream>>>(child, parent, wp, bias, out);
    } else {
        tbcnn_fallback<<<NROWS, 256, 0, stream>>>(child, parent, Wl, Wr, Wt, bias, out);
    }
}

// Round 4
// 604.510 us; speedup vs baseline: 1.3592x; 1.0131x over previous
//
#include <hip/hip_runtime.h>

#define NROWS 50000
#define CDIM 8
#define XDIM 256
#define HDIM 256

typedef __attribute__((ext_vector_type(8))) short bf16x8;  // MFMA bf16 operand (4 VGPRs)
typedef __attribute__((ext_vector_type(4))) float f32x4;   // MFMA accumulator
typedef __attribute__((ext_vector_type(2))) float f32x2;

// fp32 -> bf16 round-to-nearest-even
__device__ __forceinline__ unsigned short f2bf_rne(float f) {
    unsigned int u = __builtin_bit_cast(unsigned int, f);
    u += 0x7fffu + ((u >> 16) & 1u);
    return (unsigned short)(u >> 16);
}
// two floats -> packed u32 of 2 bf16 (lo = low 16 bits)
__device__ __forceinline__ unsigned int pack2(float lo, float hi) {
    return (unsigned int)f2bf_rne(lo) | ((unsigned int)f2bf_rne(hi) << 16);
}

// Pack W_left / W_right / W_top into MFMA A-operand fragment layout in ws:
//   tile = ((seg*8 + xc)*16 + ht), 64 lanes x 16 B.
//   value[lane][j] = W_seg[ xc*32 + (lane>>4)*8 + j ][ ht*16 + (lane&15) ]
__global__ __launch_bounds__(256) void pack_weights(
        const float* __restrict__ Wl, const float* __restrict__ Wr,
        const float* __restrict__ Wt, bf16x8* __restrict__ wp) {
    int t = blockIdx.x * 256 + threadIdx.x;   // 24576 threads
    int lane = t & 63;
    int tile = t >> 6;          // 0..383
    int ht  = tile & 15;
    int sx  = tile >> 4;
    int xc  = sx & 7;
    int seg = sx >> 3;
    const float* __restrict__ W = (seg == 0) ? Wl : (seg == 1) ? Wr : Wt;
    int x0 = xc * 32 + (lane >> 4) * 8;
    int h  = ht * 16 + (lane & 15);
    bf16x8 frag;
#pragma unroll
    for (int j = 0; j < 8; ++j)
        frag[j] = (short)f2bf_rne(W[(size_t)(x0 + j) * HDIM + h]);
    wp[t] = frag;
}

// ROUND 4: HBM saturation via global_load_lds child staging (in-flight bytes
// without VGPR cost — Little's law: need ~9.2 KB/CU in flight; register
// staging capped us at ~3.5 KB -> 2.6 TB/s).
// Block = 16 rows (grid 3125, exact). 4 waves = 4 h-quadrants (acc = 16 VGPR).
// Per xc: child slice [16r][8c][32x] = 16 KB staged to LDS (double-buffered),
// fragments (h-independent!) computed once into a shared 3 KB frag buffer.
// Swizzle both-sides: source chunk (l&7)^(l>>3); reader chunk g^(r&7).
// Sync: counted vmcnt(5) (prefetch stays in flight across barriers) + raw
// s_barrier x2 per xc; readers drain lgkmcnt(0) before the barrier that
// precedes any overwrite of their buffer.
// Accumulation chain per output element identical to round-3 (passing).
__global__ __launch_bounds__(256, 3) void tbcnn_main(
        const float* __restrict__ child, const float* __restrict__ parent,
        const bf16x8* __restrict__ wp, const float* __restrict__ bias,
        float* __restrict__ out) {
    // [buf][c][rh][row8][slot][4 floats]: 32 KiB
    __shared__ __align__(16) float chlds[2][CDIM][2][8][8][4];
    __shared__ __align__(16) bf16x8 flds[2][3 * 64];   // 6 KiB: [buf][seg*64+lane]

    const int tid  = threadIdx.x;
    const int wave = tid >> 6;
    const int lane = tid & 63;
    const int r    = lane & 15;   // row_local (frag n / D col)
    const int p2   = lane >> 4;   // producer: x-pair sel; consumer: quad
    const int blk16 = blockIdx.x * 16;

    // staging-lane decomposition for global_load_lds
    const int row8 = lane >> 3;
    const int slot = lane & 7;
    const int gch  = slot ^ row8;         // swizzled source chunk

    const float lwt[8] = {7.f/7.f, 6.f/7.f, 5.f/7.f, 4.f/7.f, 3.f/7.f, 2.f/7.f, 1.f/7.f, 0.f/7.f};
    const float rwt[8] = {0.f/7.f, 1.f/7.f, 2.f/7.f, 3.f/7.f, 4.f/7.f, 5.f/7.f, 6.f/7.f, 7.f/7.f};

    f32x4 acc[4];
#pragma unroll
    for (int t = 0; t < 4; ++t) acc[t] = (f32x4){0.f, 0.f, 0.f, 0.f};

    // ---- prologue: issue batch for xc=0 into buf 0 ----
    f32x2 pnxt;
    {
#pragma unroll
        for (int k = 0; k < 4; ++k) {
            const int i = k * 4 + wave;          // 4 instrs/wave, uniform
            const int c = i >> 1, rh = i & 1;
            const float* src = child + (size_t)(blk16 + rh * 8 + row8) * (CDIM * XDIM)
                             + c * XDIM + 0 * 32 + gch * 4;
            __builtin_amdgcn_global_load_lds(
                (const __attribute__((address_space(1))) unsigned int*)src,
                (__attribute__((address_space(3))) unsigned int*)&chlds[0][c][rh][0][0][0],
                16, 0, 0);
        }
        pnxt = *(const f32x2*)(parent + (size_t)(blk16 + r) * XDIM + 0 * 32 + wave * 8 + p2 * 2);
    }

#pragma unroll 1
    for (int xc = 0; xc < 8; ++xc) {
        const int cb = xc & 1;
        const f32x2 pcur = pnxt;

        if (xc < 7) {
            // issue batch xc+1 into chlds[cb^1] (its previous readers drained
            // at lgkmcnt(0)+barrier of iter xc-1)
#pragma unroll
            for (int k = 0; k < 4; ++k) {
                const int i = k * 4 + wave;
                const int c = i >> 1, rh = i & 1;
                const float* src = child + (size_t)(blk16 + rh * 8 + row8) * (CDIM * XDIM)
                                 + c * XDIM + (xc + 1) * 32 + gch * 4;
                __builtin_amdgcn_global_load_lds(
                    (const __attribute__((address_space(1))) unsigned int*)src,
                    (__attribute__((address_space(3))) unsigned int*)&chlds[cb ^ 1][c][rh][0][0][0],
                    16, 0, 0);
            }
            pnxt = *(const f32x2*)(parent + (size_t)(blk16 + r) * XDIM + (xc + 1) * 32 + wave * 8 + p2 * 2);
            // own outstanding: 5 new (4 gload_lds + parent). Oldest-first drain
            // completes batch xc (and any weight loads) while batch xc+1 flies.
            asm volatile("s_waitcnt vmcnt(5)" ::: "memory");
        } else {
            asm volatile("s_waitcnt vmcnt(0)" ::: "memory");
        }
        __builtin_amdgcn_s_barrier();          // Barrier1: chlds[cb] staged, visible
        asm volatile("" ::: "memory");

        // ---- reduce: frags for this xc (wave w produces x-octet w) ----
        {
            const int rh_r = r >> 3, r8 = r & 7;
            const int sl_  = (wave * 2 + (p2 >> 1)) ^ r8;   // read-side swizzle
            const int sub  = (p2 & 1) * 2;
            float sl0 = 0.f, sl1 = 0.f, sr0 = 0.f, sr1 = 0.f;
#pragma unroll
            for (int c = 0; c < CDIM; ++c) {
                f32x2 a = *(const f32x2*)&chlds[cb][c][rh_r][r8][sl_][sub];
                sl0 += a[0] * lwt[c];  sl1 += a[1] * lwt[c];
                sr0 += a[0] * rwt[c];  sr1 += a[1] * rwt[c];
            }
            ((unsigned int*)&flds[cb][0 * 64 + wave * 16 + r])[p2] = pack2(sl0, sl1);
            ((unsigned int*)&flds[cb][1 * 64 + wave * 16 + r])[p2] = pack2(sr0, sr1);
            ((unsigned int*)&flds[cb][2 * 64 + wave * 16 + r])[p2] = pack2(pcur[0], pcur[1]);
        }
        asm volatile("s_waitcnt lgkmcnt(0)" ::: "memory");  // frag writes + child reads done
        __builtin_amdgcn_s_barrier();          // Barrier2: frags visible
        asm volatile("" ::: "memory");

        // ---- MFMA: wave w consumes h-quadrant w (3 segs x 4 h-tiles) ----
#pragma unroll
        for (int seg = 0; seg < 3; ++seg) {
            const bf16x8* wb = wp + ((size_t)((seg * 8 + xc) * 16 + wave * 4)) * 64 + lane;
            bf16x8 f = flds[cb][seg * 64 + lane];
#pragma unroll
            for (int t = 0; t < 4; ++t)
                acc[t] = __builtin_amdgcn_mfma_f32_16x16x32_bf16(wb[t * 64], f, acc[t], 0, 0, 0);
        }
    }

    // ---- epilogue: bias + relu; D col = r, D row = p2*4 + j ----
    float* __restrict__ orow = out + (size_t)(blk16 + r) * HDIM;
#pragma unroll
    for (int t = 0; t < 4; ++t) {
        const int h = (wave * 4 + t) * 16 + p2 * 4;
        f32x4 b4 = *(const f32x4*)(bias + h);
        f32x4 v = acc[t];
        v[0] = fmaxf(v[0] + b4[0], 0.f);
        v[1] = fmaxf(v[1] + b4[1], 0.f);
        v[2] = fmaxf(v[2] + b4[2], 0.f);
        v[3] = fmaxf(v[3] + b4[3], 0.f);
        *(f32x4*)(orow + h) = v;
    }
}

// Correct-but-slow fallback if ws is too small for the packed weights.
__global__ __launch_bounds__(256) void tbcnn_fallback(
        const float* __restrict__ child, const float* __restrict__ parent,
        const float* __restrict__ Wl, const float* __restrict__ Wr,
        const float* __restrict__ Wt, const float* __restrict__ bias,
        float* __restrict__ out) {
    __shared__ float sl[XDIM], sr[XDIM], sp[XDIM];
    const int n = blockIdx.x;
    const int h = threadIdx.x;
    const float lwt[8] = {7.f/7.f, 6.f/7.f, 5.f/7.f, 4.f/7.f, 3.f/7.f, 2.f/7.f, 1.f/7.f, 0.f/7.f};
    const float rwt[8] = {0.f/7.f, 1.f/7.f, 2.f/7.f, 3.f/7.f, 4.f/7.f, 5.f/7.f, 6.f/7.f, 7.f/7.f};
    const float* ch = child + (size_t)n * (CDIM * XDIM);
    float al = 0.f, ar = 0.f;
#pragma unroll
    for (int c = 0; c < CDIM; ++c) {
        float v = ch[c * XDIM + h];
        al += lwt[c] * v;
        ar += rwt[c] * v;
    }
    sl[h] = al; sr[h] = ar; sp[h] = parent[(size_t)n * XDIM + h];
    __syncthreads();
    float a = bias[h];
    for (int x = 0; x < XDIM; ++x)
        a += sl[x] * Wl[(size_t)x * HDIM + h] + sr[x] * Wr[(size_t)x * HDIM + h]
           + sp[x] * Wt[(size_t)x * HDIM + h];
    out[(size_t)n * HDIM + h] = fmaxf(a, 0.f);
}

extern "C" void kernel_launch(void* const* d_in, const int* in_sizes, int n_in,
                              void* d_out, int out_size, void* d_ws, size_t ws_size,
                              hipStream_t stream) {
    const float* child  = (const float*)d_in[0];
    const float* parent = (const float*)d_in[1];
    const float* Wl     = (const float*)d_in[2];
    const float* Wr     = (const float*)d_in[3];
    const float* Wt     = (const float*)d_in[4];
    const float* bias   = (const float*)d_in[5];
    float* out = (float*)d_out;

    const size_t wp_bytes = (size_t)3 * XDIM * HDIM * sizeof(unsigned short); // 384 KiB
    if (ws_size >= wp_bytes) {
        bf16x8* wp = (bf16x8*)d_ws;
        pack_weights<<<96, 256, 0, stream>>>(Wl, Wr, Wt, wp);
        const int n_blocks = NROWS / 16;                 // 3125, exact
        tbcnn_main<<<n_blocks, 256, 0, stream>>>(child, parent, wp, bias, out);
    } else {
        tbcnn_fallback<<<NROWS, 256, 0, stream>>>(child, parent, Wl, Wr, Wt, bias, out);
    }
}